// Round 6
// baseline (2281.411 us; speedup 1.0000x reference)
//
#include <hip/hip_runtime.h>

typedef __bf16 bf16_t;
typedef __bf16 bf16x8 __attribute__((ext_vector_type(8)));
typedef float f32x4 __attribute__((ext_vector_type(4)));
typedef __fp16 f16_t;
typedef __fp16 f16x2 __attribute__((ext_vector_type(2)));
typedef __fp16 f16x8 __attribute__((ext_vector_type(8)));
typedef int i32x4 __attribute__((ext_vector_type(4)));

#define EPSBN 1e-5f
#define LOG2E 1.4426950408889634f

__device__ __forceinline__ void gload16(const void* g, void* l) {
  __builtin_amdgcn_global_load_lds(
      (const __attribute__((address_space(1))) void*)g,
      (__attribute__((address_space(3))) void*)l, 16, 0, 0);
}

__device__ __forceinline__ int h2i(f16x2 x) { union { int i; f16x2 h; } u; u.h = x; return u.i; }

__device__ __forceinline__ float exp2x(float x) {
#if __has_builtin(__builtin_amdgcn_exp2f)
  return __builtin_amdgcn_exp2f(x);
#else
  return exp2f(x);
#endif
}
__device__ __forceinline__ float rcpx(float x) {
#if __has_builtin(__builtin_amdgcn_rcpf)
  return __builtin_amdgcn_rcpf(x);
#else
  return 1.0f / x;
#endif
}

// ---------------- weight packing: fp32 -> bf16 (w1 padded 20->32 ch) ----------------
__global__ __launch_bounds__(256) void pack_w_kernel(
    const float* __restrict__ w1, const float* __restrict__ w2,
    const float* __restrict__ w3, const float* __restrict__ w4,
    const float* __restrict__ w5,
    bf16_t* __restrict__ p1, bf16_t* __restrict__ p2, bf16_t* __restrict__ p3,
    bf16_t* __restrict__ p4, bf16_t* __restrict__ p5)
{
  const int idx = blockIdx.x * 256 + threadIdx.x;
  switch (blockIdx.y) {
    case 0:
      if (idx < 256 * 160) {
        int o = idx / 160, k = idx % 160, tap = k / 32, ch = k % 32;
        p1[idx] = (bf16_t)((ch < 20) ? w1[o * 100 + tap * 20 + ch] : 0.0f);
      }
      break;
    case 1: if (idx < 512 * 1280) p2[idx] = (bf16_t)w2[idx]; break;
    case 2: if (idx < 256 * 2560) p3[idx] = (bf16_t)w3[idx]; break;
    case 3: if (idx < 128 * 768)  p4[idx] = (bf16_t)w4[idx]; break;
    default: if (idx < 128 * 384) p5[idx] = (bf16_t)w5[idx]; break;
  }
}

// ---------------- x: (B,20,L) fp32 -> (B,L,32) bf16, zero-padded channels ----------------
__global__ __launch_bounds__(256) void pack_x_kernel(
    const float* __restrict__ x, bf16_t* __restrict__ xp)
{
  __shared__ __align__(16) bf16_t Ls[256 * 32];
  const int tid = threadIdx.x;
  const int b = blockIdx.y;
  const int l0 = blockIdx.x * 256;
  bf16x8 z = {};
  #pragma unroll
  for (int i = 0; i < 4; ++i) ((bf16x8*)Ls)[tid + i * 256] = z;
  __syncthreads();
  #pragma unroll
  for (int ch = 0; ch < 20; ++ch) {
    float v = x[((size_t)b * 20 + ch) * 4096 + l0 + tid];
    Ls[tid * 32 + ch] = (bf16_t)v;
  }
  __syncthreads();
  bf16x8* dst = (bf16x8*)(xp + ((size_t)b * 4096 + l0) * 32);
  #pragma unroll
  for (int i = 0; i < 4; ++i) dst[tid + i * 256] = ((bf16x8*)Ls)[tid + i * 256];
}

// ---------------- TDNN layer as MFMA GEMM over dilated taps ----------------
template <int DIN, int C, int DIL, bool OUTF32>
__global__ __launch_bounds__(256, 2) void tdnn_gemm(
    const bf16_t* __restrict__ X, const bf16_t* __restrict__ W,
    const float* __restrict__ bias, const float* __restrict__ gg,
    const float* __restrict__ bb, const float* __restrict__ mm,
    const float* __restrict__ vv,
    bf16_t* __restrict__ Yb, float* __restrict__ Yf,
    const int Lin, const int Lo, const int N)
{
  __shared__ __align__(16) bf16_t As[128 * 32];
  __shared__ __align__(16) bf16_t Bs[128 * 32];
  const int tid = threadIdx.x;
  const int wave = tid >> 6;
  const int lane = tid & 63;
  const int l0 = blockIdx.x * 128;
  const int n0 = blockIdx.y * 128;
  const int b = blockIdx.z;
  const int lm = lane & 15;
  const int quad = lane >> 4;
  const int wm = (wave >> 1) * 64;
  const int wn = (wave & 1) * 64;
  constexpr int Ktot = C * DIN;

  const int srow = wave * 32 + (lane >> 2);
  const int scol = (lane & 3) * 8;

  const int rA0 = min(l0 + srow, Lo - 1);
  const int rA1 = min(l0 + srow + 16, Lo - 1);

  const bf16_t* Xb = X + (size_t)b * Lin * DIN;
  const bf16_t* xg0 = Xb + (size_t)rA0 * DIN + scol;
  const bf16_t* xg1 = Xb + (size_t)rA1 * DIN + scol;
  const bf16_t* wg0 = W + (size_t)(n0 + srow) * Ktot + scol;
  const bf16_t* wg1 = W + (size_t)(n0 + srow + 16) * Ktot + scol;

  bf16_t* AsW = &As[(wave * 32) * 32];
  bf16_t* BsW = &Bs[(wave * 32) * 32];

  f32x4 acc[4][4];
  f32x4 zz = {};
  #pragma unroll
  for (int i = 0; i < 4; ++i)
    #pragma unroll
    for (int j = 0; j < 4; ++j) acc[i][j] = zz;

  for (int tap = 0; tap < C; ++tap) {
    const bf16_t* xa0 = xg0 + (size_t)tap * DIL * DIN;
    const bf16_t* xa1 = xg1 + (size_t)tap * DIL * DIN;
    const bf16_t* wa0 = wg0 + tap * DIN;
    const bf16_t* wa1 = wg1 + tap * DIN;
    for (int kc = 0; kc < DIN / 32; ++kc) {
      gload16(xa0 + kc * 32, AsW);
      gload16(xa1 + kc * 32, AsW + 16 * 32);
      gload16(wa0 + kc * 32, BsW);
      gload16(wa1 + kc * 32, BsW + 16 * 32);
      __syncthreads();
      bf16x8 av[4], bv[4];
      #pragma unroll
      for (int mt = 0; mt < 4; ++mt)
        av[mt] = *(const bf16x8*)&As[(wm + mt * 16 + lm) * 32 + quad * 8];
      #pragma unroll
      for (int nt = 0; nt < 4; ++nt)
        bv[nt] = *(const bf16x8*)&Bs[(wn + nt * 16 + lm) * 32 + quad * 8];
      #pragma unroll
      for (int mt = 0; mt < 4; ++mt)
        #pragma unroll
        for (int nt = 0; nt < 4; ++nt)
          acc[mt][nt] = __builtin_amdgcn_mfma_f32_16x16x32_bf16(av[mt], bv[nt], acc[mt][nt], 0, 0, 0);
      __syncthreads();
    }
  }

  #pragma unroll
  for (int nt = 0; nt < 4; ++nt) {
    const int col = n0 + wn + nt * 16 + lm;
    const float sc = gg[col] * rsqrtf(vv[col] + EPSBN);
    const float sh = bb[col] - mm[col] * sc;
    const float bi = bias[col];
    #pragma unroll
    for (int mt = 0; mt < 4; ++mt) {
      const int rbase = l0 + wm + mt * 16 + quad * 4;
      #pragma unroll
      for (int r = 0; r < 4; ++r) {
        const int row = rbase + r;
        if (row < Lo) {
          float val = fmaxf(acc[mt][nt][r] + bi, 0.0f) * sc + sh;
          const size_t oi = ((size_t)b * Lo + row) * N + col;
          if constexpr (OUTF32) Yf[oi] = val;
          else                  Yb[oi] = (bf16_t)val;
        }
      }
    }
  }
}

// ---------------- gi0 = act5 @ wih0^T + bih0 -> padded float4 rows {r,z,n,pad} per unit ----
// r/z pre-scaled by -LOG2E (sigmoid via exp2), n pre-scaled by 2*LOG2E (tanh via exp2).
__global__ __launch_bounds__(256, 2) void gi0_kernel(
    const float* __restrict__ A5, const float* __restrict__ wih,
    const float* __restrict__ bih, float* __restrict__ GI, const int T)
{
  __shared__ __align__(16) float Xs[64 * 132];
  __shared__ __align__(16) float Ws[48 * 132];
  const int tid = threadIdx.x;
  const int b = blockIdx.y, t0 = blockIdx.x * 64;
  for (int c = tid; c < 48 * 32; c += 256) {
    int j = c >> 5, k4 = c & 31;
    *(float4*)&Ws[j * 132 + k4 * 4] = *(const float4*)&wih[j * 128 + k4 * 4];
  }
  for (int c = tid; c < 64 * 32; c += 256) {
    int r = c >> 5, k4 = c & 31;
    int tt = min(t0 + r, T - 1);
    *(float4*)&Xs[r * 132 + k4 * 4] = *(const float4*)&A5[((size_t)b * T + tt) * 128 + k4 * 4];
  }
  __syncthreads();
  const int tl = tid >> 2, jg = tid & 3;
  float acc[12];
  #pragma unroll
  for (int i = 0; i < 12; ++i) acc[i] = 0.0f;
  for (int k = 0; k < 128; k += 4) {
    float4 xv = *(const float4*)&Xs[tl * 132 + k];
    #pragma unroll
    for (int jj = 0; jj < 12; ++jj) {
      float4 wv = *(const float4*)&Ws[(jg * 12 + jj) * 132 + k];
      acc[jj] += xv.x * wv.x + xv.y * wv.y + xv.z * wv.z + xv.w * wv.w;
    }
  }
  const int t = t0 + tl;
  if (t < T) {
    float* dst = &GI[((size_t)b * T + t) * 64];
    #pragma unroll
    for (int jj = 0; jj < 12; ++jj) {
      const int row = jg * 12 + jj;
      const float s = (row >= 32) ? (2.0f * LOG2E) : (-LOG2E);
      dst[(row & 15) * 4 + (row >> 4)] = (acc[jj] + bih[row]) * s;
    }
  }
}

// ---------------- fused 2-layer GRU: MFMA matvec engine + 16 batch-chains per block -----
// 16 waves/block (4 per SIMD): independent batch recurrences co-resident on each SIMD so
// HW wave interleave hides the per-chain MFMA/bpermute/exp latency (~70% of the step).
// Per wave: lane u: L0 unit u; lane 16+u: L1 unit u (1 step behind); lanes 32-63 mirror.
// gi: ONE global_load_dwordx4 per step, 8-deep SSA ring (slot p loaded for step i+8).
// Gates: exp2/rcp with all scales folded at pack time; single-rcp rational tail.
__global__ __launch_bounds__(1024, 1) void gru_kernel(
    const float* __restrict__ GI,
    const float* __restrict__ whh0, const float* __restrict__ bhh0,
    const float* __restrict__ wih1, const float* __restrict__ bih1,
    const float* __restrict__ whh1, const float* __restrict__ bhh1,
    float* __restrict__ out, const int T)
{
  const int wid = threadIdx.x >> 6;
  const int b = blockIdx.x * 16 + wid;
  const int lane = threadIdx.x & 63;
  const int u = lane & 15;
  const bool L1 = ((lane >> 4) & 1) != 0;
  const bool STORE1 = (lane >= 16 && lane < 32);

  const int ks = (lane >> 4) * 8;                // k-slice start for A/B fragments
  constexpr float SL = -LOG2E;                   // sigmoid scale
  constexpr float SN = 2.0f * LOG2E;             // tanh scale

  // ---- static B-fragments (per-lane 8 f16 = scaled W[u][ks..ks+7]) ----
  f16x8 B1, B2, B3, B4, B5, B6, B7;
  #pragma unroll
  for (int j = 0; j < 8; ++j) {
    const int k = ks + j;
    const bool lo = (k < 16);
    const int kk = lo ? k : (k - 16);
    B1[j] = (f16_t)(lo ? SL * whh0[(0  + u) * 16 + kk] : 0.0f);
    B2[j] = (f16_t)(lo ? SL * whh0[(16 + u) * 16 + kk] : 0.0f);
    B3[j] = (f16_t)(lo ? SN * whh0[(32 + u) * 16 + kk] : 0.0f);
    B4[j] = (f16_t)(SL * (lo ? wih1[(0  + u) * 16 + kk] : whh1[(0  + u) * 16 + kk]));
    B5[j] = (f16_t)(SL * (lo ? wih1[(16 + u) * 16 + kk] : whh1[(16 + u) * 16 + kk]));
    B6[j] = (f16_t)(lo ? SN * wih1[(32 + u) * 16 + kk] : 0.0f);
    B7[j] = (f16_t)(lo ? 0.0f : SN * whh1[(32 + u) * 16 + kk]);
  }
  // ---- bias C-inputs (all 4 elems equal; D[any] = bias + y[u], pre-scaled) ----
  const float c1 = SL * bhh0[u], c2 = SL * bhh0[16 + u], c3 = SN * bhh0[32 + u];
  const float c4b = SL * (bih1[u] + bhh1[u]), c5b = SL * (bih1[16 + u] + bhh1[16 + u]);
  const float c6 = SN * bih1[32 + u], c7 = SN * bhh1[32 + u];
  const f32x4 C1 = {c1, c1, c1, c1}, C2 = {c2, c2, c2, c2}, C3 = {c3, c3, c3, c3};
  const f32x4 C4 = {c4b, c4b, c4b, c4b}, C5 = {c5b, c5b, c5b, c5b};
  const f32x4 C6 = {c6, c6, c6, c6}, C7 = {c7, c7, c7, c7};

  // ---- bpermute byte-addresses for the A-fragment gather ----
  const int ab = (lane >> 4) * 32;
  const int ad0 = ab, ad1 = ab + 8, ad2 = ab + 16, ad3 = ab + 24;

  // ---- gi ring: 8-deep, one float4 {r,z,n,pad} per step ----
  const float* gib = GI + (size_t)b * T * 64 + u * 4;
  float4 g[8];
  #pragma unroll
  for (int p = 0; p < 8; ++p)
    g[p] = *(const float4*)(gib + (size_t)p * 64);

  float hreg = 0.f;
  i32x4 aw = {0, 0, 0, 0};
  float* outp = out + (size_t)b * T * 16 + u;

  const int nb = (T + 8) / 8;                    // bodies of 8 steps (reads past T land in
  for (int body = 0; body < nb; ++body) {        // padded workspace, never consumed/stored)
    const int base = body * 8;
    #pragma unroll
    for (int p = 0; p < 8; ++p) {
      const int i = base + p;
      const float4 gv = g[p];
      g[p] = *(const float4*)(gib + (size_t)(i + 8) * 64);   // prefetch step i+8

      // ---- 7 MFMA matvecs: scaled y[u]+bias lands in every lane's D[0] ----
      const f16x8 A = __builtin_bit_cast(f16x8, aw);
      const f32x4 D1 = __builtin_amdgcn_mfma_f32_16x16x32_f16(A, B1, C1, 0, 0, 0);
      const f32x4 D2 = __builtin_amdgcn_mfma_f32_16x16x32_f16(A, B2, C2, 0, 0, 0);
      const f32x4 D3 = __builtin_amdgcn_mfma_f32_16x16x32_f16(A, B3, C3, 0, 0, 0);
      const f32x4 D4 = __builtin_amdgcn_mfma_f32_16x16x32_f16(A, B4, C4, 0, 0, 0);
      const f32x4 D5 = __builtin_amdgcn_mfma_f32_16x16x32_f16(A, B5, C5, 0, 0, 0);
      const f32x4 D6 = __builtin_amdgcn_mfma_f32_16x16x32_f16(A, B6, C6, 0, 0, 0);
      const f32x4 D7 = __builtin_amdgcn_mfma_f32_16x16x32_f16(A, B7, C7, 0, 0, 0);

      // ---- gates (exp2/rcp; single-rcp rational tail) ----
      const float pre_r = L1 ? D4[0] : (gv.x + D1[0]);
      const float pre_z = L1 ? D5[0] : (gv.y + D2[0]);
      const float aIn   = L1 ? D6[0] : gv.z;
      const float aRn   = L1 ? D7[0] : D3[0];

      const float er = exp2x(pre_r);
      const float ez = exp2x(pre_z);
      const float rr = rcpx(1.0f + er);
      const float en = exp2x(fmaf(rr, aRn, aIn));
      // hnew = n + z*(h-n) = [en*(ez+h) + (h-ez)] / [(en+1)(ez+1)]
      const float num = fmaf(en, ez + hreg, hreg - ez);
      const float den = (en + 1.0f) * (ez + 1.0f);
      float hnew = num * rcpx(den);

      if (i == 0 && L1) hnew = 0.f;              // layer-1 pipeline warm-up
      hreg = hnew;

      // ---- pack h pairs and gather A-frag for next step ----
      const int hi = __float_as_int(hreg);
#if __has_builtin(__builtin_amdgcn_mov_dpp)
      const float hp = __int_as_float(__builtin_amdgcn_mov_dpp(hi, 0xB1, 0xF, 0xF, true));
#else
      const float hp = __shfl_xor(hreg, 1);
#endif
      const int pki = h2i(__builtin_amdgcn_cvt_pkrtz(hreg, hp));  // even lanes: valid pair
      aw[0] = __builtin_amdgcn_ds_bpermute(ad0, pki);
      aw[1] = __builtin_amdgcn_ds_bpermute(ad1, pki);
      aw[2] = __builtin_amdgcn_ds_bpermute(ad2, pki);
      aw[3] = __builtin_amdgcn_ds_bpermute(ad3, pki);

      if (STORE1 && i > 0 && i <= T)
        outp[(size_t)(i - 1) * 16] = hnew;
    }
  }
}

extern "C" void kernel_launch(void* const* d_in, const int* in_sizes, int n_in,
                              void* d_out, int out_size, void* d_ws, size_t ws_size,
                              hipStream_t stream) {
  (void)in_sizes; (void)n_in; (void)out_size; (void)ws_size;
  const float* x = (const float*)d_in[0];
  const float* w1 = (const float*)d_in[1];  const float* b1 = (const float*)d_in[2];
  const float* g1 = (const float*)d_in[3];  const float* bb1 = (const float*)d_in[4];
  const float* m1 = (const float*)d_in[5];  const float* v1 = (const float*)d_in[6];
  const float* w2 = (const float*)d_in[7];  const float* b2 = (const float*)d_in[8];
  const float* g2 = (const float*)d_in[9];  const float* bb2 = (const float*)d_in[10];
  const float* m2 = (const float*)d_in[11]; const float* v2 = (const float*)d_in[12];
  const float* w3 = (const float*)d_in[13]; const float* b3 = (const float*)d_in[14];
  const float* g3 = (const float*)d_in[15]; const float* bb3 = (const float*)d_in[16];
  const float* m3 = (const float*)d_in[17]; const float* v3 = (const float*)d_in[18];
  const float* w4 = (const float*)d_in[19]; const float* b4 = (const float*)d_in[20];
  const float* g4 = (const float*)d_in[21]; const float* bb4 = (const float*)d_in[22];
  const float* m4 = (const float*)d_in[23]; const float* v4 = (const float*)d_in[24];
  const float* w5 = (const float*)d_in[25]; const float* b5 = (const float*)d_in[26];
  const float* g5 = (const float*)d_in[27]; const float* bb5 = (const float*)d_in[28];
  const float* m5 = (const float*)d_in[29]; const float* v5 = (const float*)d_in[30];
  const float* wih0 = (const float*)d_in[31];
  const float* whh0 = (const float*)d_in[32];
  const float* bih0 = (const float*)d_in[33];
  const float* bhh0 = (const float*)d_in[34];
  const float* wih1 = (const float*)d_in[35];
  const float* whh1 = (const float*)d_in[36];
  const float* bih1 = (const float*)d_in[37];
  const float* bhh1 = (const float*)d_in[38];

  char* ws = (char*)d_ws;
  size_t off = 0;
  auto alloc = [&](size_t bytes) {
    size_t r = off;
    off = (off + bytes + 255) & ~(size_t)255;
    return r;
  };
  bf16_t* p1 = (bf16_t*)(ws + alloc((size_t)256 * 160 * 2));
  bf16_t* p2 = (bf16_t*)(ws + alloc((size_t)512 * 1280 * 2));
  bf16_t* p3 = (bf16_t*)(ws + alloc((size_t)256 * 2560 * 2));
  bf16_t* p4 = (bf16_t*)(ws + alloc((size_t)128 * 768 * 2));
  bf16_t* p5 = (bf16_t*)(ws + alloc((size_t)128 * 384 * 2));
  bf16_t* xp = (bf16_t*)(ws + alloc((size_t)32 * 4096 * 32 * 2));
  char* bufA = ws + alloc((size_t)32 * 4076 * 256 * 2);
  char* bufB = ws + alloc((size_t)32 * 4056 * 512 * 2);

  bf16_t* a1 = (bf16_t*)bufA;
  bf16_t* a2 = (bf16_t*)bufB;
  bf16_t* a3 = (bf16_t*)bufA;
  bf16_t* a4 = (bf16_t*)bufB;
  float*  a5 = (float*)bufA;
  float*  gi = (float*)bufB;   // padded: 32 * 4024 * 64 floats = 33 MB << bufB size

  hipLaunchKernelGGL(pack_w_kernel, dim3(2560, 5), dim3(256), 0, stream,
                     w1, w2, w3, w4, w5, p1, p2, p3, p4, p5);
  hipLaunchKernelGGL(pack_x_kernel, dim3(16, 32), dim3(256), 0, stream, x, xp);

  hipLaunchKernelGGL((tdnn_gemm<32, 5, 5, false>), dim3(32, 2, 32), dim3(256), 0, stream,
                     xp, p1, b1, g1, bb1, m1, v1, a1, (float*)nullptr, 4096, 4076, 256);
  hipLaunchKernelGGL((tdnn_gemm<256, 5, 5, false>), dim3(32, 4, 32), dim3(256), 0, stream,
                     a1, p2, b2, g2, bb2, m2, v2, a2, (float*)nullptr, 4076, 4056, 512);
  hipLaunchKernelGGL((tdnn_gemm<512, 5, 5, false>), dim3(32, 2, 32), dim3(256), 0, stream,
                     a2, p3, b3, g3, bb3, m3, v3, a3, (float*)nullptr, 4056, 4036, 256);
  hipLaunchKernelGGL((tdnn_gemm<256, 3, 3, false>), dim3(32, 1, 32), dim3(256), 0, stream,
                     a3, p4, b4, g4, bb4, m4, v4, a4, (float*)nullptr, 4036, 4030, 128);
  hipLaunchKernelGGL((tdnn_gemm<128, 3, 3, true>), dim3(32, 1, 32), dim3(256), 0, stream,
                     a4, p5, b5, g5, bb5, m5, v5, (bf16_t*)nullptr, a5, 4030, 4024, 128);

  hipLaunchKernelGGL(gi0_kernel, dim3(63, 32), dim3(256), 0, stream, a5, wih0, bih0, gi, 4024);
  hipLaunchKernelGGL(gru_kernel, dim3(2), dim3(1024), 0, stream,
                     gi, whh0, bhh0, wih1, bih1, whh1, bhh1, (float*)d_out, 4024);
}

// Round 7
// 1698.437 us; speedup vs baseline: 1.3432x; 1.3432x over previous
//
#include <hip/hip_runtime.h>

typedef __bf16 bf16_t;
typedef __bf16 bf16x8 __attribute__((ext_vector_type(8)));
typedef float f32x4 __attribute__((ext_vector_type(4)));
typedef __fp16 f16_t;
typedef __fp16 f16x2 __attribute__((ext_vector_type(2)));
typedef __fp16 f16x8 __attribute__((ext_vector_type(8)));
typedef int i32x4 __attribute__((ext_vector_type(4)));

#define EPSBN 1e-5f
#define LOG2E 1.4426950408889634f

__device__ __forceinline__ void gload16(const void* g, void* l) {
  __builtin_amdgcn_global_load_lds(
      (const __attribute__((address_space(1))) void*)g,
      (__attribute__((address_space(3))) void*)l, 16, 0, 0);
}

__device__ __forceinline__ int h2i(f16x2 x) { union { int i; f16x2 h; } u; u.h = x; return u.i; }

__device__ __forceinline__ float exp2x(float x) {
#if __has_builtin(__builtin_amdgcn_exp2f)
  return __builtin_amdgcn_exp2f(x);
#else
  return exp2f(x);
#endif
}
__device__ __forceinline__ float rcpx(float x) {
#if __has_builtin(__builtin_amdgcn_rcpf)
  return __builtin_amdgcn_rcpf(x);
#else
  return 1.0f / x;
#endif
}

// ---------------- weight packing: fp32 -> bf16 (w1 padded 20->32 ch) ----------------
__global__ __launch_bounds__(256) void pack_w_kernel(
    const float* __restrict__ w1, const float* __restrict__ w2,
    const float* __restrict__ w3, const float* __restrict__ w4,
    const float* __restrict__ w5,
    bf16_t* __restrict__ p1, bf16_t* __restrict__ p2, bf16_t* __restrict__ p3,
    bf16_t* __restrict__ p4, bf16_t* __restrict__ p5)
{
  const int idx = blockIdx.x * 256 + threadIdx.x;
  switch (blockIdx.y) {
    case 0:
      if (idx < 256 * 160) {
        int o = idx / 160, k = idx % 160, tap = k / 32, ch = k % 32;
        p1[idx] = (bf16_t)((ch < 20) ? w1[o * 100 + tap * 20 + ch] : 0.0f);
      }
      break;
    case 1: if (idx < 512 * 1280) p2[idx] = (bf16_t)w2[idx]; break;
    case 2: if (idx < 256 * 2560) p3[idx] = (bf16_t)w3[idx]; break;
    case 3: if (idx < 128 * 768)  p4[idx] = (bf16_t)w4[idx]; break;
    default: if (idx < 128 * 384) p5[idx] = (bf16_t)w5[idx]; break;
  }
}

// ---------------- x: (B,20,L) fp32 -> (B,L,32) bf16, zero-padded channels ----------------
__global__ __launch_bounds__(256) void pack_x_kernel(
    const float* __restrict__ x, bf16_t* __restrict__ xp)
{
  __shared__ __align__(16) bf16_t Ls[256 * 32];
  const int tid = threadIdx.x;
  const int b = blockIdx.y;
  const int l0 = blockIdx.x * 256;
  bf16x8 z = {};
  #pragma unroll
  for (int i = 0; i < 4; ++i) ((bf16x8*)Ls)[tid + i * 256] = z;
  __syncthreads();
  #pragma unroll
  for (int ch = 0; ch < 20; ++ch) {
    float v = x[((size_t)b * 20 + ch) * 4096 + l0 + tid];
    Ls[tid * 32 + ch] = (bf16_t)v;
  }
  __syncthreads();
  bf16x8* dst = (bf16x8*)(xp + ((size_t)b * 4096 + l0) * 32);
  #pragma unroll
  for (int i = 0; i < 4; ++i) dst[tid + i * 256] = ((bf16x8*)Ls)[tid + i * 256];
}

// ---------------- TDNN layer as MFMA GEMM over dilated taps ----------------
template <int DIN, int C, int DIL, bool OUTF32>
__global__ __launch_bounds__(256, 2) void tdnn_gemm(
    const bf16_t* __restrict__ X, const bf16_t* __restrict__ W,
    const float* __restrict__ bias, const float* __restrict__ gg,
    const float* __restrict__ bb, const float* __restrict__ mm,
    const float* __restrict__ vv,
    bf16_t* __restrict__ Yb, float* __restrict__ Yf,
    const int Lin, const int Lo, const int N)
{
  __shared__ __align__(16) bf16_t As[128 * 32];
  __shared__ __align__(16) bf16_t Bs[128 * 32];
  const int tid = threadIdx.x;
  const int wave = tid >> 6;
  const int lane = tid & 63;
  const int l0 = blockIdx.x * 128;
  const int n0 = blockIdx.y * 128;
  const int b = blockIdx.z;
  const int lm = lane & 15;
  const int quad = lane >> 4;
  const int wm = (wave >> 1) * 64;
  const int wn = (wave & 1) * 64;
  constexpr int Ktot = C * DIN;

  const int srow = wave * 32 + (lane >> 2);
  const int scol = (lane & 3) * 8;

  const int rA0 = min(l0 + srow, Lo - 1);
  const int rA1 = min(l0 + srow + 16, Lo - 1);

  const bf16_t* Xb = X + (size_t)b * Lin * DIN;
  const bf16_t* xg0 = Xb + (size_t)rA0 * DIN + scol;
  const bf16_t* xg1 = Xb + (size_t)rA1 * DIN + scol;
  const bf16_t* wg0 = W + (size_t)(n0 + srow) * Ktot + scol;
  const bf16_t* wg1 = W + (size_t)(n0 + srow + 16) * Ktot + scol;

  bf16_t* AsW = &As[(wave * 32) * 32];
  bf16_t* BsW = &Bs[(wave * 32) * 32];

  f32x4 acc[4][4];
  f32x4 zz = {};
  #pragma unroll
  for (int i = 0; i < 4; ++i)
    #pragma unroll
    for (int j = 0; j < 4; ++j) acc[i][j] = zz;

  for (int tap = 0; tap < C; ++tap) {
    const bf16_t* xa0 = xg0 + (size_t)tap * DIL * DIN;
    const bf16_t* xa1 = xg1 + (size_t)tap * DIL * DIN;
    const bf16_t* wa0 = wg0 + tap * DIN;
    const bf16_t* wa1 = wg1 + tap * DIN;
    for (int kc = 0; kc < DIN / 32; ++kc) {
      gload16(xa0 + kc * 32, AsW);
      gload16(xa1 + kc * 32, AsW + 16 * 32);
      gload16(wa0 + kc * 32, BsW);
      gload16(wa1 + kc * 32, BsW + 16 * 32);
      __syncthreads();
      bf16x8 av[4], bv[4];
      #pragma unroll
      for (int mt = 0; mt < 4; ++mt)
        av[mt] = *(const bf16x8*)&As[(wm + mt * 16 + lm) * 32 + quad * 8];
      #pragma unroll
      for (int nt = 0; nt < 4; ++nt)
        bv[nt] = *(const bf16x8*)&Bs[(wn + nt * 16 + lm) * 32 + quad * 8];
      #pragma unroll
      for (int mt = 0; mt < 4; ++mt)
        #pragma unroll
        for (int nt = 0; nt < 4; ++nt)
          acc[mt][nt] = __builtin_amdgcn_mfma_f32_16x16x32_bf16(av[mt], bv[nt], acc[mt][nt], 0, 0, 0);
      __syncthreads();
    }
  }

  #pragma unroll
  for (int nt = 0; nt < 4; ++nt) {
    const int col = n0 + wn + nt * 16 + lm;
    const float sc = gg[col] * rsqrtf(vv[col] + EPSBN);
    const float sh = bb[col] - mm[col] * sc;
    const float bi = bias[col];
    #pragma unroll
    for (int mt = 0; mt < 4; ++mt) {
      const int rbase = l0 + wm + mt * 16 + quad * 4;
      #pragma unroll
      for (int r = 0; r < 4; ++r) {
        const int row = rbase + r;
        if (row < Lo) {
          float val = fmaxf(acc[mt][nt][r] + bi, 0.0f) * sc + sh;
          const size_t oi = ((size_t)b * Lo + row) * N + col;
          if constexpr (OUTF32) Yf[oi] = val;
          else                  Yb[oi] = (bf16_t)val;
        }
      }
    }
  }
}

// ---------------- gi0 = act5 @ wih0^T + bih0 -> padded float4 rows {r,z,n,pad} per unit ----
// r/z pre-scaled by -LOG2E (sigmoid via exp2), n pre-scaled by 2*LOG2E (tanh via exp2).
__global__ __launch_bounds__(256, 2) void gi0_kernel(
    const float* __restrict__ A5, const float* __restrict__ wih,
    const float* __restrict__ bih, float* __restrict__ GI, const int T)
{
  __shared__ __align__(16) float Xs[64 * 132];
  __shared__ __align__(16) float Ws[48 * 132];
  const int tid = threadIdx.x;
  const int b = blockIdx.y, t0 = blockIdx.x * 64;
  for (int c = tid; c < 48 * 32; c += 256) {
    int j = c >> 5, k4 = c & 31;
    *(float4*)&Ws[j * 132 + k4 * 4] = *(const float4*)&wih[j * 128 + k4 * 4];
  }
  for (int c = tid; c < 64 * 32; c += 256) {
    int r = c >> 5, k4 = c & 31;
    int tt = min(t0 + r, T - 1);
    *(float4*)&Xs[r * 132 + k4 * 4] = *(const float4*)&A5[((size_t)b * T + tt) * 128 + k4 * 4];
  }
  __syncthreads();
  const int tl = tid >> 2, jg = tid & 3;
  float acc[12];
  #pragma unroll
  for (int i = 0; i < 12; ++i) acc[i] = 0.0f;
  for (int k = 0; k < 128; k += 4) {
    float4 xv = *(const float4*)&Xs[tl * 132 + k];
    #pragma unroll
    for (int jj = 0; jj < 12; ++jj) {
      float4 wv = *(const float4*)&Ws[(jg * 12 + jj) * 132 + k];
      acc[jj] += xv.x * wv.x + xv.y * wv.y + xv.z * wv.z + xv.w * wv.w;
    }
  }
  const int t = t0 + tl;
  if (t < T) {
    float* dst = &GI[((size_t)b * T + t) * 64];
    #pragma unroll
    for (int jj = 0; jj < 12; ++jj) {
      const int row = jg * 12 + jj;
      const float s = (row >= 32) ? (2.0f * LOG2E) : (-LOG2E);
      dst[(row & 15) * 4 + (row >> 4)] = (acc[jj] + bih[row]) * s;
    }
  }
}

// ---------------- fused 2-layer GRU: MFMA matvec engine, ZERO cross-lane traffic ---------
// One wave per batch (32 blocks x 64). Lane u: L0 unit u; lane 16+u: L1 unit u (1 step
// behind); lanes 32-63 mirror.
//
// sigma-permuted A layout: A[m][k] = h_cat[sigma(k)], sigma(8q+j) = j<4 ? 4q+j
// : 16+4q+(j-4). Weight B-fragments are k-permuted to match at init (kk = 4q+(j&3),
// lo = j<4). This makes the next-step A-fragment buildable LOCALLY:
//   - A2[m][k] = h_{(k>>3)&1}[m] via one cvt_pkrtz(hreg,hreg) splat (lane l&15 IS row m)
//   - E0 = mfma(A2, Bsel k=0, 0)  -> lane reg r = h0[4q+r]   (D row layout, m89-verified)
//   - E8 = mfma(A2, Bsel k=8, 0)  -> lane reg r = h1[4q+r]
//   - aw = 4x cvt_pkrtz of E0/E8 pairs  == exactly the sigma A-fragment
// Replaces the 4x ds_bpermute (~130-150cy LDS round trip at 1 wave/CU) + DPP swap with
// ~30-40cy of MFMA+cvt on the recurrence critical path. Numerics bit-identical
// (f16(h)*1.0 accumulated in f32 == f16(h)).
// gi: ONE global_load_dwordx4 per step, 8-deep SSA ring (slot p loaded for step i+8).
// Gates: exp2/rcp, all scales folded at pack time; single-rcp rational tail.
__global__ __launch_bounds__(64, 1) void gru_kernel(
    const float* __restrict__ GI,
    const float* __restrict__ whh0, const float* __restrict__ bhh0,
    const float* __restrict__ wih1, const float* __restrict__ bih1,
    const float* __restrict__ whh1, const float* __restrict__ bhh1,
    float* __restrict__ out, const int T)
{
  const int b = blockIdx.x;
  const int lane = threadIdx.x;
  const int u = lane & 15;
  const int q = lane >> 4;                       // k-slice group 0..3
  const bool L1 = (q & 1) != 0;
  const bool STORE1 = (lane >= 16 && lane < 32);

  constexpr float SL = -LOG2E;                   // sigmoid scale
  constexpr float SN = 2.0f * LOG2E;             // tanh scale

  // ---- static B-fragments, k-permuted by sigma: element j <-> k=8q+j,
  //      W column kk = 4q + (j&3), h0-half iff j<4 ----
  f16x8 B1, B2, B3, B4, B5, B6, B7;
  #pragma unroll
  for (int j = 0; j < 8; ++j) {
    const int kk = 4 * q + (j & 3);
    const bool lo = (j < 4);
    B1[j] = (f16_t)(lo ? SL * whh0[(0  + u) * 16 + kk] : 0.0f);
    B2[j] = (f16_t)(lo ? SL * whh0[(16 + u) * 16 + kk] : 0.0f);
    B3[j] = (f16_t)(lo ? SN * whh0[(32 + u) * 16 + kk] : 0.0f);
    B4[j] = (f16_t)(SL * (lo ? wih1[(0  + u) * 16 + kk] : whh1[(0  + u) * 16 + kk]));
    B5[j] = (f16_t)(SL * (lo ? wih1[(16 + u) * 16 + kk] : whh1[(16 + u) * 16 + kk]));
    B6[j] = (f16_t)(lo ? SN * wih1[(32 + u) * 16 + kk] : 0.0f);
    B7[j] = (f16_t)(lo ? 0.0f : SN * whh1[(32 + u) * 16 + kk]);
  }
  // ---- selection Bs for the layout-transform MFMAs: delta(k=0) and delta(k=8) ----
  f16x8 S0 = {}, S8 = {};
  if (q == 0) S0[0] = (f16_t)1.0f;
  if (q == 1) S8[0] = (f16_t)1.0f;

  // ---- bias C-inputs (all 4 elems equal; D[any] = bias + y[u], pre-scaled) ----
  const float c1 = SL * bhh0[u], c2 = SL * bhh0[16 + u], c3 = SN * bhh0[32 + u];
  const float c4b = SL * (bih1[u] + bhh1[u]), c5b = SL * (bih1[16 + u] + bhh1[16 + u]);
  const float c6 = SN * bih1[32 + u], c7 = SN * bhh1[32 + u];
  const f32x4 C1 = {c1, c1, c1, c1}, C2 = {c2, c2, c2, c2}, C3 = {c3, c3, c3, c3};
  const f32x4 C4 = {c4b, c4b, c4b, c4b}, C5 = {c5b, c5b, c5b, c5b};
  const f32x4 C6 = {c6, c6, c6, c6}, C7 = {c7, c7, c7, c7};
  const f32x4 ZZ = {0.0f, 0.0f, 0.0f, 0.0f};

  // ---- gi ring: 8-deep, one float4 {r,z,n,pad} per step ----
  const float* gib = GI + (size_t)b * T * 64 + u * 4;
  float4 g[8];
  #pragma unroll
  for (int p = 0; p < 8; ++p)
    g[p] = *(const float4*)(gib + (size_t)p * 64);

  float hreg = 0.f;
  i32x4 aw = {0, 0, 0, 0};
  float* outp = out + (size_t)b * T * 16 + u;

  const int nb = (T + 8) / 8;                    // bodies of 8 steps (reads past T land in
  for (int body = 0; body < nb; ++body) {        // padded workspace, never consumed/stored)
    const int base = body * 8;
    #pragma unroll
    for (int p = 0; p < 8; ++p) {
      const int i = base + p;
      const float4 gv = g[p];
      g[p] = *(const float4*)(gib + (size_t)(i + 8) * 64);   // prefetch step i+8

      // ---- 7 MFMA matvecs: scaled y[u]+bias lands in every lane's D[0] ----
      const f16x8 A = __builtin_bit_cast(f16x8, aw);
      const f32x4 D1 = __builtin_amdgcn_mfma_f32_16x16x32_f16(A, B1, C1, 0, 0, 0);
      const f32x4 D2 = __builtin_amdgcn_mfma_f32_16x16x32_f16(A, B2, C2, 0, 0, 0);
      const f32x4 D3 = __builtin_amdgcn_mfma_f32_16x16x32_f16(A, B3, C3, 0, 0, 0);
      const f32x4 D4 = __builtin_amdgcn_mfma_f32_16x16x32_f16(A, B4, C4, 0, 0, 0);
      const f32x4 D5 = __builtin_amdgcn_mfma_f32_16x16x32_f16(A, B5, C5, 0, 0, 0);
      const f32x4 D6 = __builtin_amdgcn_mfma_f32_16x16x32_f16(A, B6, C6, 0, 0, 0);
      const f32x4 D7 = __builtin_amdgcn_mfma_f32_16x16x32_f16(A, B7, C7, 0, 0, 0);

      // ---- gates (exp2/rcp; single-rcp rational tail) ----
      const float pre_r = L1 ? D4[0] : (gv.x + D1[0]);
      const float pre_z = L1 ? D5[0] : (gv.y + D2[0]);
      const float aIn   = L1 ? D6[0] : gv.z;
      const float aRn   = L1 ? D7[0] : D3[0];

      const float er = exp2x(pre_r);
      const float ez = exp2x(pre_z);
      const float rr = rcpx(1.0f + er);
      const float en = exp2x(fmaf(rr, aRn, aIn));
      // hnew = n + z*(h-n) = [en*(ez+h) + (h-ez)] / [(en+1)(ez+1)]
      const float num = fmaf(en, ez + hreg, hreg - ez);
      const float den = (en + 1.0f) * (ez + 1.0f);
      float hnew = num * rcpx(den);

      if (i == 0 && L1) hnew = 0.f;              // layer-1 pipeline warm-up
      hreg = hnew;

      // ---- layout transform: col-layout h -> sigma A-fragment, all in-lane ----
      const int hw = h2i(__builtin_amdgcn_cvt_pkrtz(hreg, hreg));
      const i32x4 awsplat = {hw, hw, hw, hw};
      const f16x8 A2 = __builtin_bit_cast(f16x8, awsplat);
      const f32x4 E0 = __builtin_amdgcn_mfma_f32_16x16x32_f16(A2, S0, ZZ, 0, 0, 0);
      const f32x4 E8 = __builtin_amdgcn_mfma_f32_16x16x32_f16(A2, S8, ZZ, 0, 0, 0);
      aw[0] = h2i(__builtin_amdgcn_cvt_pkrtz(E0[0], E0[1]));   // h0[4q], h0[4q+1]
      aw[1] = h2i(__builtin_amdgcn_cvt_pkrtz(E0[2], E0[3]));   // h0[4q+2], h0[4q+3]
      aw[2] = h2i(__builtin_amdgcn_cvt_pkrtz(E8[0], E8[1]));   // h1[4q], h1[4q+1]
      aw[3] = h2i(__builtin_amdgcn_cvt_pkrtz(E8[2], E8[3]));   // h1[4q+2], h1[4q+3]

      if (STORE1 && i > 0 && i <= T)
        outp[(size_t)(i - 1) * 16] = hnew;
    }
  }
}

extern "C" void kernel_launch(void* const* d_in, const int* in_sizes, int n_in,
                              void* d_out, int out_size, void* d_ws, size_t ws_size,
                              hipStream_t stream) {
  (void)in_sizes; (void)n_in; (void)out_size; (void)ws_size;
  const float* x = (const float*)d_in[0];
  const float* w1 = (const float*)d_in[1];  const float* b1 = (const float*)d_in[2];
  const float* g1 = (const float*)d_in[3];  const float* bb1 = (const float*)d_in[4];
  const float* m1 = (const float*)d_in[5];  const float* v1 = (const float*)d_in[6];
  const float* w2 = (const float*)d_in[7];  const float* b2 = (const float*)d_in[8];
  const float* g2 = (const float*)d_in[9];  const float* bb2 = (const float*)d_in[10];
  const float* m2 = (const float*)d_in[11]; const float* v2 = (const float*)d_in[12];
  const float* w3 = (const float*)d_in[13]; const float* b3 = (const float*)d_in[14];
  const float* g3 = (const float*)d_in[15]; const float* bb3 = (const float*)d_in[16];
  const float* m3 = (const float*)d_in[17]; const float* v3 = (const float*)d_in[18];
  const float* w4 = (const float*)d_in[19]; const float* b4 = (const float*)d_in[20];
  const float* g4 = (const float*)d_in[21]; const float* bb4 = (const float*)d_in[22];
  const float* m4 = (const float*)d_in[23]; const float* v4 = (const float*)d_in[24];
  const float* w5 = (const float*)d_in[25]; const float* b5 = (const float*)d_in[26];
  const float* g5 = (const float*)d_in[27]; const float* bb5 = (const float*)d_in[28];
  const float* m5 = (const float*)d_in[29]; const float* v5 = (const float*)d_in[30];
  const float* wih0 = (const float*)d_in[31];
  const float* whh0 = (const float*)d_in[32];
  const float* bih0 = (const float*)d_in[33];
  const float* bhh0 = (const float*)d_in[34];
  const float* wih1 = (const float*)d_in[35];
  const float* whh1 = (const float*)d_in[36];
  const float* bih1 = (const float*)d_in[37];
  const float* bhh1 = (const float*)d_in[38];

  char* ws = (char*)d_ws;
  size_t off = 0;
  auto alloc = [&](size_t bytes) {
    size_t r = off;
    off = (off + bytes + 255) & ~(size_t)255;
    return r;
  };
  bf16_t* p1 = (bf16_t*)(ws + alloc((size_t)256 * 160 * 2));
  bf16_t* p2 = (bf16_t*)(ws + alloc((size_t)512 * 1280 * 2));
  bf16_t* p3 = (bf16_t*)(ws + alloc((size_t)256 * 2560 * 2));
  bf16_t* p4 = (bf16_t*)(ws + alloc((size_t)128 * 768 * 2));
  bf16_t* p5 = (bf16_t*)(ws + alloc((size_t)128 * 384 * 2));
  bf16_t* xp = (bf16_t*)(ws + alloc((size_t)32 * 4096 * 32 * 2));
  char* bufA = ws + alloc((size_t)32 * 4076 * 256 * 2);
  char* bufB = ws + alloc((size_t)32 * 4056 * 512 * 2);

  bf16_t* a1 = (bf16_t*)bufA;
  bf16_t* a2 = (bf16_t*)bufB;
  bf16_t* a3 = (bf16_t*)bufA;
  bf16_t* a4 = (bf16_t*)bufB;
  float*  a5 = (float*)bufA;
  float*  gi = (float*)bufB;   // padded: 32 * 4024 * 64 floats = 33 MB << bufB size

  hipLaunchKernelGGL(pack_w_kernel, dim3(2560, 5), dim3(256), 0, stream,
                     w1, w2, w3, w4, w5, p1, p2, p3, p4, p5);
  hipLaunchKernelGGL(pack_x_kernel, dim3(16, 32), dim3(256), 0, stream, x, xp);

  hipLaunchKernelGGL((tdnn_gemm<32, 5, 5, false>), dim3(32, 2, 32), dim3(256), 0, stream,
                     xp, p1, b1, g1, bb1, m1, v1, a1, (float*)nullptr, 4096, 4076, 256);
  hipLaunchKernelGGL((tdnn_gemm<256, 5, 5, false>), dim3(32, 4, 32), dim3(256), 0, stream,
                     a1, p2, b2, g2, bb2, m2, v2, a2, (float*)nullptr, 4076, 4056, 512);
  hipLaunchKernelGGL((tdnn_gemm<512, 5, 5, false>), dim3(32, 2, 32), dim3(256), 0, stream,
                     a2, p3, b3, g3, bb3, m3, v3, a3, (float*)nullptr, 4056, 4036, 256);
  hipLaunchKernelGGL((tdnn_gemm<256, 3, 3, false>), dim3(32, 1, 32), dim3(256), 0, stream,
                     a3, p4, b4, g4, bb4, m4, v4, a4, (float*)nullptr, 4036, 4030, 128);
  hipLaunchKernelGGL((tdnn_gemm<128, 3, 3, true>), dim3(32, 1, 32), dim3(256), 0, stream,
                     a4, p5, b5, g5, bb5, m5, v5, (bf16_t*)nullptr, a5, 4030, 4024, 128);

  hipLaunchKernelGGL(gi0_kernel, dim3(63, 32), dim3(256), 0, stream, a5, wih0, bih0, gi, 4024);
  hipLaunchKernelGGL(gru_kernel, dim3(32), dim3(64), 0, stream,
                     gi, whh0, bhh0, wih1, bih1, whh1, bhh1, (float*)d_out, 4024);
}

// Round 8
// 1611.749 us; speedup vs baseline: 1.4155x; 1.0538x over previous
//
#include <hip/hip_runtime.h>

typedef __bf16 bf16_t;
typedef __bf16 bf16x8 __attribute__((ext_vector_type(8)));
typedef float f32x4 __attribute__((ext_vector_type(4)));
typedef __fp16 f16_t;
typedef __fp16 f16x2 __attribute__((ext_vector_type(2)));
typedef __fp16 f16x8 __attribute__((ext_vector_type(8)));
typedef int i32x4 __attribute__((ext_vector_type(4)));

#define EPSBN 1e-5f
#define LOG2E 1.4426950408889634f

__device__ __forceinline__ void gload16(const void* g, void* l) {
  __builtin_amdgcn_global_load_lds(
      (const __attribute__((address_space(1))) void*)g,
      (__attribute__((address_space(3))) void*)l, 16, 0, 0);
}

__device__ __forceinline__ int h2i(f16x2 x) { union { int i; f16x2 h; } u; u.h = x; return u.i; }

__device__ __forceinline__ float exp2x(float x) {
#if __has_builtin(__builtin_amdgcn_exp2f)
  return __builtin_amdgcn_exp2f(x);
#else
  return exp2f(x);
#endif
}
__device__ __forceinline__ float rcpx(float x) {
#if __has_builtin(__builtin_amdgcn_rcpf)
  return __builtin_amdgcn_rcpf(x);
#else
  return 1.0f / x;
#endif
}

// ---------------- weight packing: fp32 -> bf16 (w1 padded 20->32 ch) ----------------
__global__ __launch_bounds__(256) void pack_w_kernel(
    const float* __restrict__ w1, const float* __restrict__ w2,
    const float* __restrict__ w3, const float* __restrict__ w4,
    const float* __restrict__ w5,
    bf16_t* __restrict__ p1, bf16_t* __restrict__ p2, bf16_t* __restrict__ p3,
    bf16_t* __restrict__ p4, bf16_t* __restrict__ p5)
{
  const int idx = blockIdx.x * 256 + threadIdx.x;
  switch (blockIdx.y) {
    case 0:
      if (idx < 256 * 160) {
        int o = idx / 160, k = idx % 160, tap = k / 32, ch = k % 32;
        p1[idx] = (bf16_t)((ch < 20) ? w1[o * 100 + tap * 20 + ch] : 0.0f);
      }
      break;
    case 1: if (idx < 512 * 1280) p2[idx] = (bf16_t)w2[idx]; break;
    case 2: if (idx < 256 * 2560) p3[idx] = (bf16_t)w3[idx]; break;
    case 3: if (idx < 128 * 768)  p4[idx] = (bf16_t)w4[idx]; break;
    default: if (idx < 128 * 384) p5[idx] = (bf16_t)w5[idx]; break;
  }
}

// ---------------- x: (B,20,L) fp32 -> (B,L,32) bf16, zero-padded channels ----------------
__global__ __launch_bounds__(256) void pack_x_kernel(
    const float* __restrict__ x, bf16_t* __restrict__ xp)
{
  __shared__ __align__(16) bf16_t Ls[256 * 32];
  const int tid = threadIdx.x;
  const int b = blockIdx.y;
  const int l0 = blockIdx.x * 256;
  bf16x8 z = {};
  #pragma unroll
  for (int i = 0; i < 4; ++i) ((bf16x8*)Ls)[tid + i * 256] = z;
  __syncthreads();
  #pragma unroll
  for (int ch = 0; ch < 20; ++ch) {
    float v = x[((size_t)b * 20 + ch) * 4096 + l0 + tid];
    Ls[tid * 32 + ch] = (bf16_t)v;
  }
  __syncthreads();
  bf16x8* dst = (bf16x8*)(xp + ((size_t)b * 4096 + l0) * 32);
  #pragma unroll
  for (int i = 0; i < 4; ++i) dst[tid + i * 256] = ((bf16x8*)Ls)[tid + i * 256];
}

// ---------------- TDNN layer as MFMA GEMM over dilated taps ----------------
template <int DIN, int C, int DIL, bool OUTF32>
__global__ __launch_bounds__(256, 2) void tdnn_gemm(
    const bf16_t* __restrict__ X, const bf16_t* __restrict__ W,
    const float* __restrict__ bias, const float* __restrict__ gg,
    const float* __restrict__ bb, const float* __restrict__ mm,
    const float* __restrict__ vv,
    bf16_t* __restrict__ Yb, float* __restrict__ Yf,
    const int Lin, const int Lo, const int N)
{
  __shared__ __align__(16) bf16_t As[128 * 32];
  __shared__ __align__(16) bf16_t Bs[128 * 32];
  const int tid = threadIdx.x;
  const int wave = tid >> 6;
  const int lane = tid & 63;
  const int l0 = blockIdx.x * 128;
  const int n0 = blockIdx.y * 128;
  const int b = blockIdx.z;
  const int lm = lane & 15;
  const int quad = lane >> 4;
  const int wm = (wave >> 1) * 64;
  const int wn = (wave & 1) * 64;
  constexpr int Ktot = C * DIN;

  const int srow = wave * 32 + (lane >> 2);
  const int scol = (lane & 3) * 8;

  const int rA0 = min(l0 + srow, Lo - 1);
  const int rA1 = min(l0 + srow + 16, Lo - 1);

  const bf16_t* Xb = X + (size_t)b * Lin * DIN;
  const bf16_t* xg0 = Xb + (size_t)rA0 * DIN + scol;
  const bf16_t* xg1 = Xb + (size_t)rA1 * DIN + scol;
  const bf16_t* wg0 = W + (size_t)(n0 + srow) * Ktot + scol;
  const bf16_t* wg1 = W + (size_t)(n0 + srow + 16) * Ktot + scol;

  bf16_t* AsW = &As[(wave * 32) * 32];
  bf16_t* BsW = &Bs[(wave * 32) * 32];

  f32x4 acc[4][4];
  f32x4 zz = {};
  #pragma unroll
  for (int i = 0; i < 4; ++i)
    #pragma unroll
    for (int j = 0; j < 4; ++j) acc[i][j] = zz;

  for (int tap = 0; tap < C; ++tap) {
    const bf16_t* xa0 = xg0 + (size_t)tap * DIL * DIN;
    const bf16_t* xa1 = xg1 + (size_t)tap * DIL * DIN;
    const bf16_t* wa0 = wg0 + tap * DIN;
    const bf16_t* wa1 = wg1 + tap * DIN;
    for (int kc = 0; kc < DIN / 32; ++kc) {
      gload16(xa0 + kc * 32, AsW);
      gload16(xa1 + kc * 32, AsW + 16 * 32);
      gload16(wa0 + kc * 32, BsW);
      gload16(wa1 + kc * 32, BsW + 16 * 32);
      __syncthreads();
      bf16x8 av[4], bv[4];
      #pragma unroll
      for (int mt = 0; mt < 4; ++mt)
        av[mt] = *(const bf16x8*)&As[(wm + mt * 16 + lm) * 32 + quad * 8];
      #pragma unroll
      for (int nt = 0; nt < 4; ++nt)
        bv[nt] = *(const bf16x8*)&Bs[(wn + nt * 16 + lm) * 32 + quad * 8];
      #pragma unroll
      for (int mt = 0; mt < 4; ++mt)
        #pragma unroll
        for (int nt = 0; nt < 4; ++nt)
          acc[mt][nt] = __builtin_amdgcn_mfma_f32_16x16x32_bf16(av[mt], bv[nt], acc[mt][nt], 0, 0, 0);
      __syncthreads();
    }
  }

  #pragma unroll
  for (int nt = 0; nt < 4; ++nt) {
    const int col = n0 + wn + nt * 16 + lm;
    const float sc = gg[col] * rsqrtf(vv[col] + EPSBN);
    const float sh = bb[col] - mm[col] * sc;
    const float bi = bias[col];
    #pragma unroll
    for (int mt = 0; mt < 4; ++mt) {
      const int rbase = l0 + wm + mt * 16 + quad * 4;
      #pragma unroll
      for (int r = 0; r < 4; ++r) {
        const int row = rbase + r;
        if (row < Lo) {
          float val = fmaxf(acc[mt][nt][r] + bi, 0.0f) * sc + sh;
          const size_t oi = ((size_t)b * Lo + row) * N + col;
          if constexpr (OUTF32) Yf[oi] = val;
          else                  Yb[oi] = (bf16_t)val;
        }
      }
    }
  }
}

// ---------------- gi0 = act5 @ wih0^T + bih0 -> padded float4 rows {r,z,n,pad} per unit ----
// r/z pre-scaled by -LOG2E (sigmoid via exp2), n pre-scaled by 2*LOG2E (tanh via exp2).
__global__ __launch_bounds__(256, 2) void gi0_kernel(
    const float* __restrict__ A5, const float* __restrict__ wih,
    const float* __restrict__ bih, float* __restrict__ GI, const int T)
{
  __shared__ __align__(16) float Xs[64 * 132];
  __shared__ __align__(16) float Ws[48 * 132];
  const int tid = threadIdx.x;
  const int b = blockIdx.y, t0 = blockIdx.x * 64;
  for (int c = tid; c < 48 * 32; c += 256) {
    int j = c >> 5, k4 = c & 31;
    *(float4*)&Ws[j * 132 + k4 * 4] = *(const float4*)&wih[j * 128 + k4 * 4];
  }
  for (int c = tid; c < 64 * 32; c += 256) {
    int r = c >> 5, k4 = c & 31;
    int tt = min(t0 + r, T - 1);
    *(float4*)&Xs[r * 132 + k4 * 4] = *(const float4*)&A5[((size_t)b * T + tt) * 128 + k4 * 4];
  }
  __syncthreads();
  const int tl = tid >> 2, jg = tid & 3;
  float acc[12];
  #pragma unroll
  for (int i = 0; i < 12; ++i) acc[i] = 0.0f;
  for (int k = 0; k < 128; k += 4) {
    float4 xv = *(const float4*)&Xs[tl * 132 + k];
    #pragma unroll
    for (int jj = 0; jj < 12; ++jj) {
      float4 wv = *(const float4*)&Ws[(jg * 12 + jj) * 132 + k];
      acc[jj] += xv.x * wv.x + xv.y * wv.y + xv.z * wv.z + xv.w * wv.w;
    }
  }
  const int t = t0 + tl;
  if (t < T) {
    float* dst = &GI[((size_t)b * T + t) * 64];
    #pragma unroll
    for (int jj = 0; jj < 12; ++jj) {
      const int row = jg * 12 + jj;
      const float s = (row >= 32) ? (2.0f * LOG2E) : (-LOG2E);
      dst[(row & 15) * 4 + (row >> 4)] = (acc[jj] + bih[row]) * s;
    }
  }
}

// ---------------- fused 2-layer GRU: MFMA matvec engine + bpermute gather (best-known) ----
// One wave per batch (32 blocks x 64). Lane u: L0 unit u; lane 16+u: L1 unit u (1 step
// behind); lanes 32-63 mirror (their aw slices supply the h1 half of the k-range).
// gi: ONE global_load_dwordx4 per step, 8-deep SSA ring (slot p loaded for step i+8).
// Gather: pack h pairs (even lane 2p holds f16x2 pair p of h_cat) then 4x ds_bpermute.
// [R7 lesson: replacing bpermute with a 2nd MFMA stage costs +96cy/step - MFMA dependent
//  readback latency ~100cy at 1 wave/SIMD; bpermute leg ~60cy. Keep bpermute.]
// Gates: exp2/rcp, scales folded at pack time; single-rcp rational tail.
__global__ __launch_bounds__(64, 1) void gru_kernel(
    const float* __restrict__ GI,
    const float* __restrict__ whh0, const float* __restrict__ bhh0,
    const float* __restrict__ wih1, const float* __restrict__ bih1,
    const float* __restrict__ whh1, const float* __restrict__ bhh1,
    float* __restrict__ out, const int T)
{
  const int b = blockIdx.x;
  const int lane = threadIdx.x;
  const int u = lane & 15;
  const bool L1 = ((lane >> 4) & 1) != 0;
  const bool STORE1 = (lane >= 16 && lane < 32);

  const int ks = (lane >> 4) * 8;                // k-slice start for A/B fragments
  constexpr float SL = -LOG2E;                   // sigmoid scale
  constexpr float SN = 2.0f * LOG2E;             // tanh scale

  // ---- static B-fragments (per-lane 8 f16 = scaled W[u][ks..ks+7]) ----
  f16x8 B1, B2, B3, B4, B5, B6, B7;
  #pragma unroll
  for (int j = 0; j < 8; ++j) {
    const int k = ks + j;
    const bool lo = (k < 16);
    const int kk = lo ? k : (k - 16);
    B1[j] = (f16_t)(lo ? SL * whh0[(0  + u) * 16 + kk] : 0.0f);
    B2[j] = (f16_t)(lo ? SL * whh0[(16 + u) * 16 + kk] : 0.0f);
    B3[j] = (f16_t)(lo ? SN * whh0[(32 + u) * 16 + kk] : 0.0f);
    B4[j] = (f16_t)(SL * (lo ? wih1[(0  + u) * 16 + kk] : whh1[(0  + u) * 16 + kk]));
    B5[j] = (f16_t)(SL * (lo ? wih1[(16 + u) * 16 + kk] : whh1[(16 + u) * 16 + kk]));
    B6[j] = (f16_t)(lo ? SN * wih1[(32 + u) * 16 + kk] : 0.0f);
    B7[j] = (f16_t)(lo ? 0.0f : SN * whh1[(32 + u) * 16 + kk]);
  }
  // ---- bias C-inputs (all 4 elems equal; D[any] = bias + y[u], pre-scaled) ----
  const float c1 = SL * bhh0[u], c2 = SL * bhh0[16 + u], c3 = SN * bhh0[32 + u];
  const float c4b = SL * (bih1[u] + bhh1[u]), c5b = SL * (bih1[16 + u] + bhh1[16 + u]);
  const float c6 = SN * bih1[32 + u], c7 = SN * bhh1[32 + u];
  const f32x4 C1 = {c1, c1, c1, c1}, C2 = {c2, c2, c2, c2}, C3 = {c3, c3, c3, c3};
  const f32x4 C4 = {c4b, c4b, c4b, c4b}, C5 = {c5b, c5b, c5b, c5b};
  const f32x4 C6 = {c6, c6, c6, c6}, C7 = {c7, c7, c7, c7};

  // ---- bpermute byte-addresses for the A-fragment gather ----
  const int ab = (lane >> 4) * 32;
  const int ad0 = ab, ad1 = ab + 8, ad2 = ab + 16, ad3 = ab + 24;

  // ---- gi ring: 8-deep, one float4 {r,z,n,pad} per step ----
  const float* gib = GI + (size_t)b * T * 64 + u * 4;
  float4 g[8];
  #pragma unroll
  for (int p = 0; p < 8; ++p)
    g[p] = *(const float4*)(gib + (size_t)p * 64);

  float hreg = 0.f;
  i32x4 aw = {0, 0, 0, 0};
  float* outp = out + (size_t)b * T * 16 + u;

  const int nb = (T + 8) / 8;                    // bodies of 8 steps (reads past T land in
  for (int body = 0; body < nb; ++body) {        // padded workspace, never consumed/stored)
    const int base = body * 8;
    #pragma unroll
    for (int p = 0; p < 8; ++p) {
      const int i = base + p;
      const float4 gv = g[p];
      g[p] = *(const float4*)(gib + (size_t)(i + 8) * 64);   // prefetch step i+8

      // ---- 7 MFMA matvecs: scaled y[u]+bias lands in every lane's D[0] ----
      const f16x8 A = __builtin_bit_cast(f16x8, aw);
      const f32x4 D1 = __builtin_amdgcn_mfma_f32_16x16x32_f16(A, B1, C1, 0, 0, 0);
      const f32x4 D2 = __builtin_amdgcn_mfma_f32_16x16x32_f16(A, B2, C2, 0, 0, 0);
      const f32x4 D3 = __builtin_amdgcn_mfma_f32_16x16x32_f16(A, B3, C3, 0, 0, 0);
      const f32x4 D4 = __builtin_amdgcn_mfma_f32_16x16x32_f16(A, B4, C4, 0, 0, 0);
      const f32x4 D5 = __builtin_amdgcn_mfma_f32_16x16x32_f16(A, B5, C5, 0, 0, 0);
      const f32x4 D6 = __builtin_amdgcn_mfma_f32_16x16x32_f16(A, B6, C6, 0, 0, 0);
      const f32x4 D7 = __builtin_amdgcn_mfma_f32_16x16x32_f16(A, B7, C7, 0, 0, 0);

      // ---- gates (exp2/rcp; single-rcp rational tail) ----
      const float pre_r = L1 ? D4[0] : (gv.x + D1[0]);
      const float pre_z = L1 ? D5[0] : (gv.y + D2[0]);
      const float aIn   = L1 ? D6[0] : gv.z;
      const float aRn   = L1 ? D7[0] : D3[0];

      const float er = exp2x(pre_r);
      const float ez = exp2x(pre_z);
      const float rr = rcpx(1.0f + er);
      const float en = exp2x(fmaf(rr, aRn, aIn));
      // hnew = n + z*(h-n) = [en*(ez+h) + (h-ez)] / [(en+1)(ez+1)]
      const float num = fmaf(en, ez + hreg, hreg - ez);
      const float den = (en + 1.0f) * (ez + 1.0f);
      float hnew = num * rcpx(den);

      if (i == 0 && L1) hnew = 0.f;              // layer-1 pipeline warm-up
      hreg = hnew;

      // ---- pack h pairs and gather A-frag for next step ----
      const int hi = __float_as_int(hreg);
#if __has_builtin(__builtin_amdgcn_mov_dpp)
      const float hp = __int_as_float(__builtin_amdgcn_mov_dpp(hi, 0xB1, 0xF, 0xF, true));
#else
      const float hp = __shfl_xor(hreg, 1);
#endif
      const int pki = h2i(__builtin_amdgcn_cvt_pkrtz(hreg, hp));  // even lanes: valid pair
      aw[0] = __builtin_amdgcn_ds_bpermute(ad0, pki);
      aw[1] = __builtin_amdgcn_ds_bpermute(ad1, pki);
      aw[2] = __builtin_amdgcn_ds_bpermute(ad2, pki);
      aw[3] = __builtin_amdgcn_ds_bpermute(ad3, pki);

      if (STORE1 && i > 0 && i <= T)
        outp[(size_t)(i - 1) * 16] = hnew;
    }
  }
}

extern "C" void kernel_launch(void* const* d_in, const int* in_sizes, int n_in,
                              void* d_out, int out_size, void* d_ws, size_t ws_size,
                              hipStream_t stream) {
  (void)in_sizes; (void)n_in; (void)out_size; (void)ws_size;
  const float* x = (const float*)d_in[0];
  const float* w1 = (const float*)d_in[1];  const float* b1 = (const float*)d_in[2];
  const float* g1 = (const float*)d_in[3];  const float* bb1 = (const float*)d_in[4];
  const float* m1 = (const float*)d_in[5];  const float* v1 = (const float*)d_in[6];
  const float* w2 = (const float*)d_in[7];  const float* b2 = (const float*)d_in[8];
  const float* g2 = (const float*)d_in[9];  const float* bb2 = (const float*)d_in[10];
  const float* m2 = (const float*)d_in[11]; const float* v2 = (const float*)d_in[12];
  const float* w3 = (const float*)d_in[13]; const float* b3 = (const float*)d_in[14];
  const float* g3 = (const float*)d_in[15]; const float* bb3 = (const float*)d_in[16];
  const float* m3 = (const float*)d_in[17]; const float* v3 = (const float*)d_in[18];
  const float* w4 = (const float*)d_in[19]; const float* b4 = (const float*)d_in[20];
  const float* g4 = (const float*)d_in[21]; const float* bb4 = (const float*)d_in[22];
  const float* m4 = (const float*)d_in[23]; const float* v4 = (const float*)d_in[24];
  const float* w5 = (const float*)d_in[25]; const float* b5 = (const float*)d_in[26];
  const float* g5 = (const float*)d_in[27]; const float* bb5 = (const float*)d_in[28];
  const float* m5 = (const float*)d_in[29]; const float* v5 = (const float*)d_in[30];
  const float* wih0 = (const float*)d_in[31];
  const float* whh0 = (const float*)d_in[32];
  const float* bih0 = (const float*)d_in[33];
  const float* bhh0 = (const float*)d_in[34];
  const float* wih1 = (const float*)d_in[35];
  const float* whh1 = (const float*)d_in[36];
  const float* bih1 = (const float*)d_in[37];
  const float* bhh1 = (const float*)d_in[38];

  char* ws = (char*)d_ws;
  size_t off = 0;
  auto alloc = [&](size_t bytes) {
    size_t r = off;
    off = (off + bytes + 255) & ~(size_t)255;
    return r;
  };
  bf16_t* p1 = (bf16_t*)(ws + alloc((size_t)256 * 160 * 2));
  bf16_t* p2 = (bf16_t*)(ws + alloc((size_t)512 * 1280 * 2));
  bf16_t* p3 = (bf16_t*)(ws + alloc((size_t)256 * 2560 * 2));
  bf16_t* p4 = (bf16_t*)(ws + alloc((size_t)128 * 768 * 2));
  bf16_t* p5 = (bf16_t*)(ws + alloc((size_t)128 * 384 * 2));
  bf16_t* xp = (bf16_t*)(ws + alloc((size_t)32 * 4096 * 32 * 2));
  char* bufA = ws + alloc((size_t)32 * 4076 * 256 * 2);
  char* bufB = ws + alloc((size_t)32 * 4056 * 512 * 2);

  bf16_t* a1 = (bf16_t*)bufA;
  bf16_t* a2 = (bf16_t*)bufB;
  bf16_t* a3 = (bf16_t*)bufA;
  bf16_t* a4 = (bf16_t*)bufB;
  float*  a5 = (float*)bufA;
  float*  gi = (float*)bufB;   // padded: 32 * 4024 * 64 floats = 33 MB << bufB size

  hipLaunchKernelGGL(pack_w_kernel, dim3(2560, 5), dim3(256), 0, stream,
                     w1, w2, w3, w4, w5, p1, p2, p3, p4, p5);
  hipLaunchKernelGGL(pack_x_kernel, dim3(16, 32), dim3(256), 0, stream, x, xp);

  hipLaunchKernelGGL((tdnn_gemm<32, 5, 5, false>), dim3(32, 2, 32), dim3(256), 0, stream,
                     xp, p1, b1, g1, bb1, m1, v1, a1, (float*)nullptr, 4096, 4076, 256);
  hipLaunchKernelGGL((tdnn_gemm<256, 5, 5, false>), dim3(32, 4, 32), dim3(256), 0, stream,
                     a1, p2, b2, g2, bb2, m2, v2, a2, (float*)nullptr, 4076, 4056, 512);
  hipLaunchKernelGGL((tdnn_gemm<512, 5, 5, false>), dim3(32, 2, 32), dim3(256), 0, stream,
                     a2, p3, b3, g3, bb3, m3, v3, a3, (float*)nullptr, 4056, 4036, 256);
  hipLaunchKernelGGL((tdnn_gemm<256, 3, 3, false>), dim3(32, 1, 32), dim3(256), 0, stream,
                     a3, p4, b4, g4, bb4, m4, v4, a4, (float*)nullptr, 4036, 4030, 128);
  hipLaunchKernelGGL((tdnn_gemm<128, 3, 3, true>), dim3(32, 1, 32), dim3(256), 0, stream,
                     a4, p5, b5, g5, bb5, m5, v5, (bf16_t*)nullptr, a5, 4030, 4024, 128);

  hipLaunchKernelGGL(gi0_kernel, dim3(63, 32), dim3(256), 0, stream, a5, wih0, bih0, gi, 4024);
  hipLaunchKernelGGL(gru_kernel, dim3(32), dim3(64), 0, stream,
                     gi, whh0, bhh0, wih1, bih1, whh1, bhh1, (float*)d_out, 4024);
}

// Round 9
// 1491.298 us; speedup vs baseline: 1.5298x; 1.0808x over previous
//
#include <hip/hip_runtime.h>

typedef __bf16 bf16_t;
typedef __bf16 bf16x8 __attribute__((ext_vector_type(8)));
typedef float f32x4 __attribute__((ext_vector_type(4)));
typedef __fp16 f16_t;
typedef __fp16 f16x2 __attribute__((ext_vector_type(2)));
typedef __fp16 f16x8 __attribute__((ext_vector_type(8)));
typedef int i32x4 __attribute__((ext_vector_type(4)));

#define EPSBN 1e-5f
#define LOG2E 1.4426950408889634f

__device__ __forceinline__ void gload16(const void* g, void* l) {
  __builtin_amdgcn_global_load_lds(
      (const __attribute__((address_space(1))) void*)g,
      (__attribute__((address_space(3))) void*)l, 16, 0, 0);
}

__device__ __forceinline__ int h2i(f16x2 x) { union { int i; f16x2 h; } u; u.h = x; return u.i; }

__device__ __forceinline__ float exp2x(float x) {
#if __has_builtin(__builtin_amdgcn_exp2f)
  return __builtin_amdgcn_exp2f(x);
#else
  return exp2f(x);
#endif
}
__device__ __forceinline__ float rcpx(float x) {
#if __has_builtin(__builtin_amdgcn_rcpf)
  return __builtin_amdgcn_rcpf(x);
#else
  return 1.0f / x;
#endif
}

// ---------------- weight packing: fp32 -> bf16 (w1 padded 20->32 ch) ----------------
__global__ __launch_bounds__(256) void pack_w_kernel(
    const float* __restrict__ w1, const float* __restrict__ w2,
    const float* __restrict__ w3, const float* __restrict__ w4,
    const float* __restrict__ w5,
    bf16_t* __restrict__ p1, bf16_t* __restrict__ p2, bf16_t* __restrict__ p3,
    bf16_t* __restrict__ p4, bf16_t* __restrict__ p5)
{
  const int idx = blockIdx.x * 256 + threadIdx.x;
  switch (blockIdx.y) {
    case 0:
      if (idx < 256 * 160) {
        int o = idx / 160, k = idx % 160, tap = k / 32, ch = k % 32;
        p1[idx] = (bf16_t)((ch < 20) ? w1[o * 100 + tap * 20 + ch] : 0.0f);
      }
      break;
    case 1: if (idx < 512 * 1280) p2[idx] = (bf16_t)w2[idx]; break;
    case 2: if (idx < 256 * 2560) p3[idx] = (bf16_t)w3[idx]; break;
    case 3: if (idx < 128 * 768)  p4[idx] = (bf16_t)w4[idx]; break;
    default: if (idx < 128 * 384) p5[idx] = (bf16_t)w5[idx]; break;
  }
}

// ---------------- x: (B,20,L) fp32 -> (B,L,32) bf16, zero-padded channels ----------------
__global__ __launch_bounds__(256) void pack_x_kernel(
    const float* __restrict__ x, bf16_t* __restrict__ xp)
{
  __shared__ __align__(16) bf16_t Ls[256 * 32];
  const int tid = threadIdx.x;
  const int b = blockIdx.y;
  const int l0 = blockIdx.x * 256;
  bf16x8 z = {};
  #pragma unroll
  for (int i = 0; i < 4; ++i) ((bf16x8*)Ls)[tid + i * 256] = z;
  __syncthreads();
  #pragma unroll
  for (int ch = 0; ch < 20; ++ch) {
    float v = x[((size_t)b * 20 + ch) * 4096 + l0 + tid];
    Ls[tid * 32 + ch] = (bf16_t)v;
  }
  __syncthreads();
  bf16x8* dst = (bf16x8*)(xp + ((size_t)b * 4096 + l0) * 32);
  #pragma unroll
  for (int i = 0; i < 4; ++i) dst[tid + i * 256] = ((bf16x8*)Ls)[tid + i * 256];
}

// ---------------- TDNN layer, BK=32 path (DIN==32 / layer 1 only; proven) ----------------
template <int DIN, int C, int DIL, bool OUTF32>
__global__ __launch_bounds__(256, 2) void tdnn_gemm(
    const bf16_t* __restrict__ X, const bf16_t* __restrict__ W,
    const float* __restrict__ bias, const float* __restrict__ gg,
    const float* __restrict__ bb, const float* __restrict__ mm,
    const float* __restrict__ vv,
    bf16_t* __restrict__ Yb, float* __restrict__ Yf,
    const int Lin, const int Lo, const int N)
{
  __shared__ __align__(16) bf16_t As[128 * 32];
  __shared__ __align__(16) bf16_t Bs[128 * 32];
  const int tid = threadIdx.x;
  const int wave = tid >> 6;
  const int lane = tid & 63;
  const int l0 = blockIdx.x * 128;
  const int n0 = blockIdx.y * 128;
  const int b = blockIdx.z;
  const int lm = lane & 15;
  const int quad = lane >> 4;
  const int wm = (wave >> 1) * 64;
  const int wn = (wave & 1) * 64;
  constexpr int Ktot = C * DIN;

  const int srow = wave * 32 + (lane >> 2);
  const int scol = (lane & 3) * 8;

  const int rA0 = min(l0 + srow, Lo - 1);
  const int rA1 = min(l0 + srow + 16, Lo - 1);

  const bf16_t* Xb = X + (size_t)b * Lin * DIN;
  const bf16_t* xg0 = Xb + (size_t)rA0 * DIN + scol;
  const bf16_t* xg1 = Xb + (size_t)rA1 * DIN + scol;
  const bf16_t* wg0 = W + (size_t)(n0 + srow) * Ktot + scol;
  const bf16_t* wg1 = W + (size_t)(n0 + srow + 16) * Ktot + scol;

  bf16_t* AsW = &As[(wave * 32) * 32];
  bf16_t* BsW = &Bs[(wave * 32) * 32];

  f32x4 acc[4][4];
  f32x4 zz = {};
  #pragma unroll
  for (int i = 0; i < 4; ++i)
    #pragma unroll
    for (int j = 0; j < 4; ++j) acc[i][j] = zz;

  for (int tap = 0; tap < C; ++tap) {
    const bf16_t* xa0 = xg0 + (size_t)tap * DIL * DIN;
    const bf16_t* xa1 = xg1 + (size_t)tap * DIL * DIN;
    const bf16_t* wa0 = wg0 + tap * DIN;
    const bf16_t* wa1 = wg1 + tap * DIN;
    for (int kc = 0; kc < DIN / 32; ++kc) {
      gload16(xa0 + kc * 32, AsW);
      gload16(xa1 + kc * 32, AsW + 16 * 32);
      gload16(wa0 + kc * 32, BsW);
      gload16(wa1 + kc * 32, BsW + 16 * 32);
      __syncthreads();
      bf16x8 av[4], bv[4];
      #pragma unroll
      for (int mt = 0; mt < 4; ++mt)
        av[mt] = *(const bf16x8*)&As[(wm + mt * 16 + lm) * 32 + quad * 8];
      #pragma unroll
      for (int nt = 0; nt < 4; ++nt)
        bv[nt] = *(const bf16x8*)&Bs[(wn + nt * 16 + lm) * 32 + quad * 8];
      #pragma unroll
      for (int mt = 0; mt < 4; ++mt)
        #pragma unroll
        for (int nt = 0; nt < 4; ++nt)
          acc[mt][nt] = __builtin_amdgcn_mfma_f32_16x16x32_bf16(av[mt], bv[nt], acc[mt][nt], 0, 0, 0);
      __syncthreads();
    }
  }

  #pragma unroll
  for (int nt = 0; nt < 4; ++nt) {
    const int col = n0 + wn + nt * 16 + lm;
    const float sc = gg[col] * rsqrtf(vv[col] + EPSBN);
    const float sh = bb[col] - mm[col] * sc;
    const float bi = bias[col];
    #pragma unroll
    for (int mt = 0; mt < 4; ++mt) {
      const int rbase = l0 + wm + mt * 16 + quad * 4;
      #pragma unroll
      for (int r = 0; r < 4; ++r) {
        const int row = rbase + r;
        if (row < Lo) {
          float val = fmaxf(acc[mt][nt][r] + bi, 0.0f) * sc + sh;
          const size_t oi = ((size_t)b * Lo + row) * N + col;
          if constexpr (OUTF32) Yf[oi] = val;
          else                  Yb[oi] = (bf16_t)val;
        }
      }
    }
  }
}

// ---------------- TDNN layer, BK=64 path (DIN%64==0): half the barriers ------------------
// LDS rows are 128B (bank-aligned) -> XOR-swizzle chunks: physical chunk = c ^ (row&7).
// gload_lds dest stays LINEAR (wave-uniform base + lane*16, rule m104); the swizzle is
// applied by permuting the per-lane GLOBAL source column (c = (lane&7) ^ (lane>>3)) and
// XOR-ing the ds_read offset. Read spread: (ks*4+quad)^(lm&7) -> 8 lanes / 4-bank group
// (uniform, conflict-free). One barrier pair per 64 K (vs 2 at BK=32).
template <int DIN, int C, int DIL, bool OUTF32>
__global__ __launch_bounds__(256, 2) void tdnn_gemm64(
    const bf16_t* __restrict__ X, const bf16_t* __restrict__ W,
    const float* __restrict__ bias, const float* __restrict__ gg,
    const float* __restrict__ bb, const float* __restrict__ mm,
    const float* __restrict__ vv,
    bf16_t* __restrict__ Yb, float* __restrict__ Yf,
    const int Lin, const int Lo, const int N)
{
  __shared__ __align__(16) bf16_t As[128 * 64];
  __shared__ __align__(16) bf16_t Bs[128 * 64];
  const int tid = threadIdx.x;
  const int wave = tid >> 6;
  const int lane = tid & 63;
  const int l0 = blockIdx.x * 128;
  const int n0 = blockIdx.y * 128;
  const int b = blockIdx.z;
  const int lm = lane & 15;
  const int quad = lane >> 4;
  const int wm = (wave >> 1) * 64;
  const int wn = (wave & 1) * 64;
  constexpr int Ktot = C * DIN;

  // staging: lane covers physical chunk (lane&7) of row wave*32 + 8*it + (lane>>3);
  // that slot holds logical chunk c = (lane&7) ^ (lane>>3)  (since (8*it)&7 == 0)
  const int srow8 = lane >> 3;                    // 0..7
  const int sc = ((lane & 7) ^ srow8) * 8;        // logical element offset 0..56

  const bf16_t* Xb = X + (size_t)b * Lin * DIN;
  const bf16_t* xsrc[4];
  const bf16_t* wsrc[4];
  #pragma unroll
  for (int it = 0; it < 4; ++it) {
    const int r = wave * 32 + 8 * it + srow8;
    const int ra = min(l0 + r, Lo - 1);
    xsrc[it] = Xb + (size_t)ra * DIN + sc;
    wsrc[it] = W + (size_t)(n0 + r) * Ktot + sc;
  }
  bf16_t* AsW = &As[wave * 32 * 64];
  bf16_t* BsW = &Bs[wave * 32 * 64];

  f32x4 acc[4][4];
  f32x4 zz = {};
  #pragma unroll
  for (int i = 0; i < 4; ++i)
    #pragma unroll
    for (int j = 0; j < 4; ++j) acc[i][j] = zz;

  for (int tap = 0; tap < C; ++tap) {
    const size_t xoff = (size_t)tap * DIL * DIN;
    const int woff = tap * DIN;
    for (int kc = 0; kc < DIN / 64; ++kc) {
      #pragma unroll
      for (int it = 0; it < 4; ++it) {
        gload16(xsrc[it] + xoff + kc * 64, AsW + it * 512);
        gload16(wsrc[it] + woff + kc * 64, BsW + it * 512);
      }
      __syncthreads();
      #pragma unroll
      for (int ks = 0; ks < 2; ++ks) {
        bf16x8 av[4], bv[4];
        #pragma unroll
        for (int mt = 0; mt < 4; ++mt) {
          const int row = wm + mt * 16 + lm;
          av[mt] = *(const bf16x8*)&As[row * 64 + (((ks * 4 + quad) ^ (row & 7)) * 8)];
        }
        #pragma unroll
        for (int nt = 0; nt < 4; ++nt) {
          const int row = wn + nt * 16 + lm;
          bv[nt] = *(const bf16x8*)&Bs[row * 64 + (((ks * 4 + quad) ^ (row & 7)) * 8)];
        }
        #pragma unroll
        for (int mt = 0; mt < 4; ++mt)
          #pragma unroll
          for (int nt = 0; nt < 4; ++nt)
            acc[mt][nt] = __builtin_amdgcn_mfma_f32_16x16x32_bf16(av[mt], bv[nt], acc[mt][nt], 0, 0, 0);
      }
      __syncthreads();
    }
  }

  #pragma unroll
  for (int nt = 0; nt < 4; ++nt) {
    const int col = n0 + wn + nt * 16 + lm;
    const float sc2 = gg[col] * rsqrtf(vv[col] + EPSBN);
    const float sh = bb[col] - mm[col] * sc2;
    const float bi = bias[col];
    #pragma unroll
    for (int mt = 0; mt < 4; ++mt) {
      const int rbase = l0 + wm + mt * 16 + quad * 4;
      #pragma unroll
      for (int r = 0; r < 4; ++r) {
        const int row = rbase + r;
        if (row < Lo) {
          float val = fmaxf(acc[mt][nt][r] + bi, 0.0f) * sc2 + sh;
          const size_t oi = ((size_t)b * Lo + row) * N + col;
          if constexpr (OUTF32) Yf[oi] = val;
          else                  Yb[oi] = (bf16_t)val;
        }
      }
    }
  }
}

// ---------------- gi0 = act5 @ wih0^T + bih0 -> padded float4 rows {r,z,n,pad} per unit ----
// r/z pre-scaled by -LOG2E (sigmoid via exp2), n pre-scaled by 2*LOG2E (tanh via exp2).
__global__ __launch_bounds__(256, 2) void gi0_kernel(
    const float* __restrict__ A5, const float* __restrict__ wih,
    const float* __restrict__ bih, float* __restrict__ GI, const int T)
{
  __shared__ __align__(16) float Xs[64 * 132];
  __shared__ __align__(16) float Ws[48 * 132];
  const int tid = threadIdx.x;
  const int b = blockIdx.y, t0 = blockIdx.x * 64;
  for (int c = tid; c < 48 * 32; c += 256) {
    int j = c >> 5, k4 = c & 31;
    *(float4*)&Ws[j * 132 + k4 * 4] = *(const float4*)&wih[j * 128 + k4 * 4];
  }
  for (int c = tid; c < 64 * 32; c += 256) {
    int r = c >> 5, k4 = c & 31;
    int tt = min(t0 + r, T - 1);
    *(float4*)&Xs[r * 132 + k4 * 4] = *(const float4*)&A5[((size_t)b * T + tt) * 128 + k4 * 4];
  }
  __syncthreads();
  const int tl = tid >> 2, jg = tid & 3;
  float acc[12];
  #pragma unroll
  for (int i = 0; i < 12; ++i) acc[i] = 0.0f;
  for (int k = 0; k < 128; k += 4) {
    float4 xv = *(const float4*)&Xs[tl * 132 + k];
    #pragma unroll
    for (int jj = 0; jj < 12; ++jj) {
      float4 wv = *(const float4*)&Ws[(jg * 12 + jj) * 132 + k];
      acc[jj] += xv.x * wv.x + xv.y * wv.y + xv.z * wv.z + xv.w * wv.w;
    }
  }
  const int t = t0 + tl;
  if (t < T) {
    float* dst = &GI[((size_t)b * T + t) * 64];
    #pragma unroll
    for (int jj = 0; jj < 12; ++jj) {
      const int row = jg * 12 + jj;
      const float s = (row >= 32) ? (2.0f * LOG2E) : (-LOG2E);
      dst[(row & 15) * 4 + (row >> 4)] = (acc[jj] + bih[row]) * s;
    }
  }
}

// ---------------- fused 2-layer GRU: R4-verified best configuration ----------------------
// One wave per batch (32 blocks x 64). MFMA matvec engine + bpermute gather + 8-deep gi
// ring + two-rcp gates (R4 = 463 cy/step). [R5 readlane-select, R6 wave-stack, R7 MFMA
// gather, R8 rational tail: all measured slower. Keep exactly this.]
__global__ __launch_bounds__(64, 1) void gru_kernel(
    const float* __restrict__ GI,
    const float* __restrict__ whh0, const float* __restrict__ bhh0,
    const float* __restrict__ wih1, const float* __restrict__ bih1,
    const float* __restrict__ whh1, const float* __restrict__ bhh1,
    float* __restrict__ out, const int T)
{
  const int b = blockIdx.x;
  const int lane = threadIdx.x;
  const int u = lane & 15;
  const bool L1 = ((lane >> 4) & 1) != 0;
  const bool STORE1 = (lane >= 16 && lane < 32);

  const int ks = (lane >> 4) * 8;                // k-slice start for A/B fragments
  constexpr float SL = -LOG2E;                   // sigmoid scale
  constexpr float SN = 2.0f * LOG2E;             // tanh scale

  // ---- static B-fragments (per-lane 8 f16 = scaled W[u][ks..ks+7]) ----
  f16x8 B1, B2, B3, B4, B5, B6, B7;
  #pragma unroll
  for (int j = 0; j < 8; ++j) {
    const int k = ks + j;
    const bool lo = (k < 16);
    const int kk = lo ? k : (k - 16);
    B1[j] = (f16_t)(lo ? SL * whh0[(0  + u) * 16 + kk] : 0.0f);
    B2[j] = (f16_t)(lo ? SL * whh0[(16 + u) * 16 + kk] : 0.0f);
    B3[j] = (f16_t)(lo ? SN * whh0[(32 + u) * 16 + kk] : 0.0f);
    B4[j] = (f16_t)(SL * (lo ? wih1[(0  + u) * 16 + kk] : whh1[(0  + u) * 16 + kk]));
    B5[j] = (f16_t)(SL * (lo ? wih1[(16 + u) * 16 + kk] : whh1[(16 + u) * 16 + kk]));
    B6[j] = (f16_t)(lo ? SN * wih1[(32 + u) * 16 + kk] : 0.0f);
    B7[j] = (f16_t)(lo ? 0.0f : SN * whh1[(32 + u) * 16 + kk]);
  }
  // ---- bias C-inputs (all 4 elems equal; D[any] = bias + y[u], pre-scaled) ----
  const float c1 = SL * bhh0[u], c2 = SL * bhh0[16 + u], c3 = SN * bhh0[32 + u];
  const float c4b = SL * (bih1[u] + bhh1[u]), c5b = SL * (bih1[16 + u] + bhh1[16 + u]);
  const float c6 = SN * bih1[32 + u], c7 = SN * bhh1[32 + u];
  const f32x4 C1 = {c1, c1, c1, c1}, C2 = {c2, c2, c2, c2}, C3 = {c3, c3, c3, c3};
  const f32x4 C4 = {c4b, c4b, c4b, c4b}, C5 = {c5b, c5b, c5b, c5b};
  const f32x4 C6 = {c6, c6, c6, c6}, C7 = {c7, c7, c7, c7};

  // ---- bpermute byte-addresses for the A-fragment gather ----
  const int ab = (lane >> 4) * 32;
  const int ad0 = ab, ad1 = ab + 8, ad2 = ab + 16, ad3 = ab + 24;

  // ---- gi ring: 8-deep, one float4 {r,z,n,pad} per step ----
  const float* gib = GI + (size_t)b * T * 64 + u * 4;
  float4 g[8];
  #pragma unroll
  for (int p = 0; p < 8; ++p)
    g[p] = *(const float4*)(gib + (size_t)p * 64);

  float hreg = 0.f;
  i32x4 aw = {0, 0, 0, 0};
  float* outp = out + (size_t)b * T * 16 + u;

  const int nb = (T + 8) / 8;                    // bodies of 8 steps (reads past T land in
  for (int body = 0; body < nb; ++body) {        // padded workspace, never consumed/stored)
    const int base = body * 8;
    #pragma unroll
    for (int p = 0; p < 8; ++p) {
      const int i = base + p;
      const float4 gv = g[p];
      g[p] = *(const float4*)(gib + (size_t)(i + 8) * 64);   // prefetch step i+8

      // ---- 7 MFMA matvecs: scaled y[u]+bias lands in every lane's D[0] ----
      const f16x8 A = __builtin_bit_cast(f16x8, aw);
      const f32x4 D1 = __builtin_amdgcn_mfma_f32_16x16x32_f16(A, B1, C1, 0, 0, 0);
      const f32x4 D2 = __builtin_amdgcn_mfma_f32_16x16x32_f16(A, B2, C2, 0, 0, 0);
      const f32x4 D3 = __builtin_amdgcn_mfma_f32_16x16x32_f16(A, B3, C3, 0, 0, 0);
      const f32x4 D4 = __builtin_amdgcn_mfma_f32_16x16x32_f16(A, B4, C4, 0, 0, 0);
      const f32x4 D5 = __builtin_amdgcn_mfma_f32_16x16x32_f16(A, B5, C5, 0, 0, 0);
      const f32x4 D6 = __builtin_amdgcn_mfma_f32_16x16x32_f16(A, B6, C6, 0, 0, 0);
      const f32x4 D7 = __builtin_amdgcn_mfma_f32_16x16x32_f16(A, B7, C7, 0, 0, 0);

      // ---- gates (exp2/rcp; R4-verified two-rcp tail) ----
      const float pre_r = L1 ? D4[0] : (gv.x + D1[0]);
      const float pre_z = L1 ? D5[0] : (gv.y + D2[0]);
      const float aIn   = L1 ? D6[0] : gv.z;
      const float aRn   = L1 ? D7[0] : D3[0];

      const float r = rcpx(1.0f + exp2x(pre_r));
      const float z = rcpx(1.0f + exp2x(pre_z));
      const float e = exp2x(fmaf(r, aRn, aIn));
      const float n = fmaf(-2.0f, rcpx(e + 1.0f), 1.0f);
      float hnew = fmaf(z, hreg - n, n);

      if (i == 0 && L1) hnew = 0.f;              // layer-1 pipeline warm-up
      hreg = hnew;

      // ---- pack h pairs and gather A-frag for next step ----
      const int hi = __float_as_int(hreg);
#if __has_builtin(__builtin_amdgcn_mov_dpp)
      const float hp = __int_as_float(__builtin_amdgcn_mov_dpp(hi, 0xB1, 0xF, 0xF, true));
#else
      const float hp = __shfl_xor(hreg, 1);
#endif
      const int pki = h2i(__builtin_amdgcn_cvt_pkrtz(hreg, hp));  // even lanes: valid pair
      aw[0] = __builtin_amdgcn_ds_bpermute(ad0, pki);
      aw[1] = __builtin_amdgcn_ds_bpermute(ad1, pki);
      aw[2] = __builtin_amdgcn_ds_bpermute(ad2, pki);
      aw[3] = __builtin_amdgcn_ds_bpermute(ad3, pki);

      if (STORE1 && i > 0 && i <= T)
        outp[(size_t)(i - 1) * 16] = hnew;
    }
  }
}

extern "C" void kernel_launch(void* const* d_in, const int* in_sizes, int n_in,
                              void* d_out, int out_size, void* d_ws, size_t ws_size,
                              hipStream_t stream) {
  (void)in_sizes; (void)n_in; (void)out_size; (void)ws_size;
  const float* x = (const float*)d_in[0];
  const float* w1 = (const float*)d_in[1];  const float* b1 = (const float*)d_in[2];
  const float* g1 = (const float*)d_in[3];  const float* bb1 = (const float*)d_in[4];
  const float* m1 = (const float*)d_in[5];  const float* v1 = (const float*)d_in[6];
  const float* w2 = (const float*)d_in[7];  const float* b2 = (const float*)d_in[8];
  const float* g2 = (const float*)d_in[9];  const float* bb2 = (const float*)d_in[10];
  const float* m2 = (const float*)d_in[11]; const float* v2 = (const float*)d_in[12];
  const float* w3 = (const float*)d_in[13]; const float* b3 = (const float*)d_in[14];
  const float* g3 = (const float*)d_in[15]; const float* bb3 = (const float*)d_in[16];
  const float* m3 = (const float*)d_in[17]; const float* v3 = (const float*)d_in[18];
  const float* w4 = (const float*)d_in[19]; const float* b4 = (const float*)d_in[20];
  const float* g4 = (const float*)d_in[21]; const float* bb4 = (const float*)d_in[22];
  const float* m4 = (const float*)d_in[23]; const float* v4 = (const float*)d_in[24];
  const float* w5 = (const float*)d_in[25]; const float* b5 = (const float*)d_in[26];
  const float* g5 = (const float*)d_in[27]; const float* bb5 = (const float*)d_in[28];
  const float* m5 = (const float*)d_in[29]; const float* v5 = (const float*)d_in[30];
  const float* wih0 = (const float*)d_in[31];
  const float* whh0 = (const float*)d_in[32];
  const float* bih0 = (const float*)d_in[33];
  const float* bhh0 = (const float*)d_in[34];
  const float* wih1 = (const float*)d_in[35];
  const float* whh1 = (const float*)d_in[36];
  const float* bih1 = (const float*)d_in[37];
  const float* bhh1 = (const float*)d_in[38];

  char* ws = (char*)d_ws;
  size_t off = 0;
  auto alloc = [&](size_t bytes) {
    size_t r = off;
    off = (off + bytes + 255) & ~(size_t)255;
    return r;
  };
  bf16_t* p1 = (bf16_t*)(ws + alloc((size_t)256 * 160 * 2));
  bf16_t* p2 = (bf16_t*)(ws + alloc((size_t)512 * 1280 * 2));
  bf16_t* p3 = (bf16_t*)(ws + alloc((size_t)256 * 2560 * 2));
  bf16_t* p4 = (bf16_t*)(ws + alloc((size_t)128 * 768 * 2));
  bf16_t* p5 = (bf16_t*)(ws + alloc((size_t)128 * 384 * 2));
  bf16_t* xp = (bf16_t*)(ws + alloc((size_t)32 * 4096 * 32 * 2));
  char* bufA = ws + alloc((size_t)32 * 4076 * 256 * 2);
  char* bufB = ws + alloc((size_t)32 * 4056 * 512 * 2);

  bf16_t* a1 = (bf16_t*)bufA;
  bf16_t* a2 = (bf16_t*)bufB;
  bf16_t* a3 = (bf16_t*)bufA;
  bf16_t* a4 = (bf16_t*)bufB;
  float*  a5 = (float*)bufA;
  float*  gi = (float*)bufB;   // padded: 32 * 4024 * 64 floats = 33 MB << bufB size

  hipLaunchKernelGGL(pack_w_kernel, dim3(2560, 5), dim3(256), 0, stream,
                     w1, w2, w3, w4, w5, p1, p2, p3, p4, p5);
  hipLaunchKernelGGL(pack_x_kernel, dim3(16, 32), dim3(256), 0, stream, x, xp);

  hipLaunchKernelGGL((tdnn_gemm<32, 5, 5, false>), dim3(32, 2, 32), dim3(256), 0, stream,
                     xp, p1, b1, g1, bb1, m1, v1, a1, (float*)nullptr, 4096, 4076, 256);
  hipLaunchKernelGGL((tdnn_gemm64<256, 5, 5, false>), dim3(32, 4, 32), dim3(256), 0, stream,
                     a1, p2, b2, g2, bb2, m2, v2, a2, (float*)nullptr, 4076, 4056, 512);
  hipLaunchKernelGGL((tdnn_gemm64<512, 5, 5, false>), dim3(32, 2, 32), dim3(256), 0, stream,
                     a2, p3, b3, g3, bb3, m3, v3, a3, (float*)nullptr, 4056, 4036, 256);
  hipLaunchKernelGGL((tdnn_gemm64<256, 3, 3, false>), dim3(32, 1, 32), dim3(256), 0, stream,
                     a3, p4, b4, g4, bb4, m4, v4, a4, (float*)nullptr, 4036, 4030, 128);
  hipLaunchKernelGGL((tdnn_gemm64<128, 3, 3, true>), dim3(32, 1, 32), dim3(256), 0, stream,
                     a4, p5, b5, g5, bb5, m5, v5, (bf16_t*)nullptr, a5, 4030, 4024, 128);

  hipLaunchKernelGGL(gi0_kernel, dim3(63, 32), dim3(256), 0, stream, a5, wih0, bih0, gi, 4024);
  hipLaunchKernelGGL(gru_kernel, dim3(32), dim3(64), 0, stream,
                     gi, whh0, bhh0, wih1, bih1, whh1, bhh1, (float*)d_out, 4024);
}